// Round 1
// baseline (80.202 us; speedup 1.0000x reference)
//
#include <hip/hip_runtime.h>

// out[m] = init_c2w[f] @ [[R(r[f]), t[f]],[0,0,0,1]],  f = frame_idx[m]
// r[0], t[0] treated as zero (reference does r.at[0].set(0)).
// One thread per output 4x4 matrix. Memory-bound: ~128 MB write dominates.

__global__ __launch_bounds__(256) void learnpose_kernel(
    const float* __restrict__ r,
    const float* __restrict__ t,
    const float* __restrict__ init_c2w,
    const int*   __restrict__ frame_idx,
    float*       __restrict__ out,
    int M)
{
    int m = blockIdx.x * blockDim.x + threadIdx.x;
    if (m >= M) return;

    int f = frame_idx[m];

    float x, y, z, tx, ty, tz;
    if (f == 0) {
        x = y = z = tx = ty = tz = 0.0f;
    } else {
        const float* rp = r + 3 * (size_t)f;
        const float* tp = t + 3 * (size_t)f;
        x = rp[0]; y = rp[1]; z = rp[2];
        tx = tp[0]; ty = tp[1]; tz = tp[2];
    }

    // Rodrigues: R = I + A*skew + B*skew^2, A = sin(n)/n, B = (1-cos(n))/n^2
    float n2 = x * x + y * y + z * z;
    float n = sqrtf(n2) + 1e-15f;
    float s, c;
    sincosf(n, &s, &c);
    float A = s / n;
    float B = (1.0f - c) / (n * n);

    float xx = x * x, yy = y * y, zz = z * z;
    float xy = x * y, xz = x * z, yz = y * z;

    float R00 = 1.0f - B * (yy + zz);
    float R01 = -A * z + B * xy;
    float R02 =  A * y + B * xz;
    float R10 =  A * z + B * xy;
    float R11 = 1.0f - B * (xx + zz);
    float R12 = -A * x + B * yz;
    float R20 = -A * y + B * xz;
    float R21 =  A * x + B * yz;
    float R22 = 1.0f - B * (xx + yy);

    // out[i][j] = sum_k init[i][k] * c2w[k][j]; c2w rows 0..2 = [R | t], row 3 = [0 0 0 1]
    const float4* ip = reinterpret_cast<const float4*>(init_c2w + (size_t)f * 16);
    float4* op = reinterpret_cast<float4*>(out + (size_t)m * 16);

#pragma unroll
    for (int i = 0; i < 4; ++i) {
        float4 a = ip[i];
        float4 o;
        o.x = a.x * R00 + a.y * R10 + a.z * R20;
        o.y = a.x * R01 + a.y * R11 + a.z * R21;
        o.z = a.x * R02 + a.y * R12 + a.z * R22;
        o.w = a.x * tx  + a.y * ty  + a.z * tz + a.w;
        op[i] = o;
    }
}

extern "C" void kernel_launch(void* const* d_in, const int* in_sizes, int n_in,
                              void* d_out, int out_size, void* d_ws, size_t ws_size,
                              hipStream_t stream) {
    const float* r        = (const float*)d_in[0];
    const float* t        = (const float*)d_in[1];
    const float* init_c2w = (const float*)d_in[2];
    const int*   fidx     = (const int*)d_in[3];
    float* out = (float*)d_out;

    int M = in_sizes[3];
    int block = 256;
    int grid = (M + block - 1) / block;
    learnpose_kernel<<<grid, block, 0, stream>>>(r, t, init_c2w, fidx, out, M);
}

// Round 2
// 56.928 us; speedup vs baseline: 1.4088x; 1.4088x over previous
//
#include <hip/hip_runtime.h>

// Two-phase:
//  P1: pose[f] = init_c2w[f] @ [[R(r[f]), t[f]],[0,0,0,1]]  (N rows, into d_ws)
//  P2: out[m] = pose[frame_idx[m]]  -- pure 64B gather, 4 threads/matrix
// r[0], t[0] treated as zero (reference does r.at[0].set(0)).

__global__ __launch_bounds__(256) void pose_table_kernel(
    const float* __restrict__ r,
    const float* __restrict__ t,
    const float* __restrict__ init_c2w,
    float*       __restrict__ table,
    int N)
{
    int f = blockIdx.x * blockDim.x + threadIdx.x;
    if (f >= N) return;

    float x, y, z, tx, ty, tz;
    if (f == 0) {
        x = y = z = tx = ty = tz = 0.0f;
    } else {
        const float* rp = r + 3 * (size_t)f;
        const float* tp = t + 3 * (size_t)f;
        x = rp[0]; y = rp[1]; z = rp[2];
        tx = tp[0]; ty = tp[1]; tz = tp[2];
    }

    // Rodrigues: R = I + A*skew + B*skew^2
    float n2 = x * x + y * y + z * z;
    float n = sqrtf(n2) + 1e-15f;
    float s, c;
    sincosf(n, &s, &c);
    float A = s / n;
    float B = (1.0f - c) / (n * n);

    float xx = x * x, yy = y * y, zz = z * z;
    float xy = x * y, xz = x * z, yz = y * z;

    float R00 = 1.0f - B * (yy + zz);
    float R01 = -A * z + B * xy;
    float R02 =  A * y + B * xz;
    float R10 =  A * z + B * xy;
    float R11 = 1.0f - B * (xx + zz);
    float R12 = -A * x + B * yz;
    float R20 = -A * y + B * xz;
    float R21 =  A * x + B * yz;
    float R22 = 1.0f - B * (xx + yy);

    const float4* ip = reinterpret_cast<const float4*>(init_c2w + (size_t)f * 16);
    float4* op = reinterpret_cast<float4*>(table + (size_t)f * 16);

#pragma unroll
    for (int i = 0; i < 4; ++i) {
        float4 a = ip[i];
        float4 o;
        o.x = a.x * R00 + a.y * R10 + a.z * R20;
        o.y = a.x * R01 + a.y * R11 + a.z * R21;
        o.z = a.x * R02 + a.y * R12 + a.z * R22;
        o.w = a.x * tx  + a.y * ty  + a.z * tz + a.w;
        op[i] = o;
    }
}

// 4 threads per output matrix; thread g moves one float4.
__global__ __launch_bounds__(256) void gather_kernel(
    const float4* __restrict__ table,   // N x 4 float4
    const int*    __restrict__ frame_idx,
    float4*       __restrict__ out,     // M x 4 float4
    int M4)                             // = 4*M
{
    int g = blockIdx.x * blockDim.x + threadIdx.x;
    if (g >= M4) return;
    int m = g >> 2;
    int j = g & 3;
    int f = frame_idx[m];
    out[g] = table[(size_t)f * 4 + j];
}

// Fallback: fused single-pass (R1 kernel) if ws too small.
__global__ __launch_bounds__(256) void learnpose_fused_kernel(
    const float* __restrict__ r,
    const float* __restrict__ t,
    const float* __restrict__ init_c2w,
    const int*   __restrict__ frame_idx,
    float*       __restrict__ out,
    int M)
{
    int m = blockIdx.x * blockDim.x + threadIdx.x;
    if (m >= M) return;

    int f = frame_idx[m];
    float x, y, z, tx, ty, tz;
    if (f == 0) {
        x = y = z = tx = ty = tz = 0.0f;
    } else {
        const float* rp = r + 3 * (size_t)f;
        const float* tp = t + 3 * (size_t)f;
        x = rp[0]; y = rp[1]; z = rp[2];
        tx = tp[0]; ty = tp[1]; tz = tp[2];
    }
    float n2 = x * x + y * y + z * z;
    float n = sqrtf(n2) + 1e-15f;
    float s, c;
    sincosf(n, &s, &c);
    float A = s / n;
    float B = (1.0f - c) / (n * n);
    float xx = x * x, yy = y * y, zz = z * z;
    float xy = x * y, xz = x * z, yz = y * z;
    float R00 = 1.0f - B * (yy + zz);
    float R01 = -A * z + B * xy;
    float R02 =  A * y + B * xz;
    float R10 =  A * z + B * xy;
    float R11 = 1.0f - B * (xx + zz);
    float R12 = -A * x + B * yz;
    float R20 = -A * y + B * xz;
    float R21 =  A * x + B * yz;
    float R22 = 1.0f - B * (xx + yy);

    const float4* ip = reinterpret_cast<const float4*>(init_c2w + (size_t)f * 16);
    float4* op = reinterpret_cast<float4*>(out + (size_t)m * 16);
#pragma unroll
    for (int i = 0; i < 4; ++i) {
        float4 a = ip[i];
        float4 o;
        o.x = a.x * R00 + a.y * R10 + a.z * R20;
        o.y = a.x * R01 + a.y * R11 + a.z * R21;
        o.z = a.x * R02 + a.y * R12 + a.z * R22;
        o.w = a.x * tx  + a.y * ty  + a.z * tz + a.w;
        op[i] = o;
    }
}

extern "C" void kernel_launch(void* const* d_in, const int* in_sizes, int n_in,
                              void* d_out, int out_size, void* d_ws, size_t ws_size,
                              hipStream_t stream) {
    const float* r        = (const float*)d_in[0];
    const float* t        = (const float*)d_in[1];
    const float* init_c2w = (const float*)d_in[2];
    const int*   fidx     = (const int*)d_in[3];
    float* out = (float*)d_out;

    int N = in_sizes[0] / 3;
    int M = in_sizes[3];

    size_t table_bytes = (size_t)N * 16 * sizeof(float);
    if (ws_size >= table_bytes) {
        float* table = (float*)d_ws;
        int block = 256;
        int grid1 = (N + block - 1) / block;
        pose_table_kernel<<<grid1, block, 0, stream>>>(r, t, init_c2w, table, N);

        int M4 = 4 * M;
        int grid2 = (M4 + block - 1) / block;
        gather_kernel<<<grid2, block, 0, stream>>>(
            (const float4*)table, fidx, (float4*)out, M4);
    } else {
        int block = 256;
        int grid = (M + block - 1) / block;
        learnpose_fused_kernel<<<grid, block, 0, stream>>>(r, t, init_c2w, fidx, out, M);
    }
}

// Round 4
// 51.417 us; speedup vs baseline: 1.5598x; 1.1072x over previous
//
#include <hip/hip_runtime.h>

// Two-phase:
//  P1: pose[f] = init_c2w[f] @ [[R(r[f]), t[f]],[0,0,0,1]]  (N rows, into d_ws)
//  P2: out[m] = pose[frame_idx[m]]  -- 64B gather, 4 threads/matrix,
//      2 records per thread (ILP), non-temporal stores (don't thrash L2).
// r[0], t[0] treated as zero (reference does r.at[0].set(0)).

typedef float v4f __attribute__((ext_vector_type(4)));  // nontemporal-builtin compatible

__global__ __launch_bounds__(256) void pose_table_kernel(
    const float* __restrict__ r,
    const float* __restrict__ t,
    const float* __restrict__ init_c2w,
    float*       __restrict__ table,
    int N)
{
    int f = blockIdx.x * blockDim.x + threadIdx.x;
    if (f >= N) return;

    float x, y, z, tx, ty, tz;
    if (f == 0) {
        x = y = z = tx = ty = tz = 0.0f;
    } else {
        const float* rp = r + 3 * (size_t)f;
        const float* tp = t + 3 * (size_t)f;
        x = rp[0]; y = rp[1]; z = rp[2];
        tx = tp[0]; ty = tp[1]; tz = tp[2];
    }

    // Rodrigues: R = I + A*skew + B*skew^2
    float n2 = x * x + y * y + z * z;
    float n = sqrtf(n2) + 1e-15f;
    float s, c;
    sincosf(n, &s, &c);
    float A = s / n;
    float B = (1.0f - c) / (n * n);

    float xx = x * x, yy = y * y, zz = z * z;
    float xy = x * y, xz = x * z, yz = y * z;

    float R00 = 1.0f - B * (yy + zz);
    float R01 = -A * z + B * xy;
    float R02 =  A * y + B * xz;
    float R10 =  A * z + B * xy;
    float R11 = 1.0f - B * (xx + zz);
    float R12 = -A * x + B * yz;
    float R20 = -A * y + B * xz;
    float R21 =  A * x + B * yz;
    float R22 = 1.0f - B * (xx + yy);

    const v4f* ip = reinterpret_cast<const v4f*>(init_c2w + (size_t)f * 16);
    v4f* op = reinterpret_cast<v4f*>(table + (size_t)f * 16);

#pragma unroll
    for (int i = 0; i < 4; ++i) {
        v4f a = ip[i];
        v4f o;
        o.x = a.x * R00 + a.y * R10 + a.z * R20;
        o.y = a.x * R01 + a.y * R11 + a.z * R21;
        o.z = a.x * R02 + a.y * R12 + a.z * R22;
        o.w = a.x * tx  + a.y * ty  + a.z * tz + a.w;
        op[i] = o;
    }
}

// 4 threads per matrix; each thread moves TWO float4s (independent records,
// doubling outstanding gathers). Stores are non-temporal: the 128 MB write
// stream must not evict the 6.4 MB pose table from L2.
__global__ __launch_bounds__(256) void gather_kernel(
    const v4f* __restrict__ table,   // N x 4 v4f
    const int* __restrict__ frame_idx,
    v4f*       __restrict__ out,     // M x 4 v4f
    int M4,                          // = 4*M
    int half)                        // = ceil(M4/2)
{
    int g = blockIdx.x * blockDim.x + threadIdx.x;
    if (g >= half) return;
    int g2 = g + half;

    int m0 = g >> 2,  j0 = g & 3;
    int f0 = frame_idx[m0];
    v4f v0 = table[(size_t)f0 * 4 + j0];

    if (g2 < M4) {
        int m1 = g2 >> 2, j1 = g2 & 3;
        int f1 = frame_idx[m1];
        v4f v1 = table[(size_t)f1 * 4 + j1];
        __builtin_nontemporal_store(v0, &out[g]);
        __builtin_nontemporal_store(v1, &out[g2]);
    } else {
        __builtin_nontemporal_store(v0, &out[g]);
    }
}

// Fallback: fused single-pass if ws too small.
__global__ __launch_bounds__(256) void learnpose_fused_kernel(
    const float* __restrict__ r,
    const float* __restrict__ t,
    const float* __restrict__ init_c2w,
    const int*   __restrict__ frame_idx,
    float*       __restrict__ out,
    int M)
{
    int m = blockIdx.x * blockDim.x + threadIdx.x;
    if (m >= M) return;

    int f = frame_idx[m];
    float x, y, z, tx, ty, tz;
    if (f == 0) {
        x = y = z = tx = ty = tz = 0.0f;
    } else {
        const float* rp = r + 3 * (size_t)f;
        const float* tp = t + 3 * (size_t)f;
        x = rp[0]; y = rp[1]; z = rp[2];
        tx = tp[0]; ty = tp[1]; tz = tp[2];
    }
    float n2 = x * x + y * y + z * z;
    float n = sqrtf(n2) + 1e-15f;
    float s, c;
    sincosf(n, &s, &c);
    float A = s / n;
    float B = (1.0f - c) / (n * n);
    float xx = x * x, yy = y * y, zz = z * z;
    float xy = x * y, xz = x * z, yz = y * z;
    float R00 = 1.0f - B * (yy + zz);
    float R01 = -A * z + B * xy;
    float R02 =  A * y + B * xz;
    float R10 =  A * z + B * xy;
    float R11 = 1.0f - B * (xx + zz);
    float R12 = -A * x + B * yz;
    float R20 = -A * y + B * xz;
    float R21 =  A * x + B * yz;
    float R22 = 1.0f - B * (xx + yy);

    const v4f* ip = reinterpret_cast<const v4f*>(init_c2w + (size_t)f * 16);
    v4f* op = reinterpret_cast<v4f*>(out + (size_t)m * 16);
#pragma unroll
    for (int i = 0; i < 4; ++i) {
        v4f a = ip[i];
        v4f o;
        o.x = a.x * R00 + a.y * R10 + a.z * R20;
        o.y = a.x * R01 + a.y * R11 + a.z * R21;
        o.z = a.x * R02 + a.y * R12 + a.z * R22;
        o.w = a.x * tx  + a.y * ty  + a.z * tz + a.w;
        op[i] = o;
    }
}

extern "C" void kernel_launch(void* const* d_in, const int* in_sizes, int n_in,
                              void* d_out, int out_size, void* d_ws, size_t ws_size,
                              hipStream_t stream) {
    const float* r        = (const float*)d_in[0];
    const float* t        = (const float*)d_in[1];
    const float* init_c2w = (const float*)d_in[2];
    const int*   fidx     = (const int*)d_in[3];
    float* out = (float*)d_out;

    int N = in_sizes[0] / 3;
    int M = in_sizes[3];

    size_t table_bytes = (size_t)N * 16 * sizeof(float);
    if (ws_size >= table_bytes) {
        float* table = (float*)d_ws;
        int block = 256;
        int grid1 = (N + block - 1) / block;
        pose_table_kernel<<<grid1, block, 0, stream>>>(r, t, init_c2w, table, N);

        int M4 = 4 * M;
        int half = (M4 + 1) / 2;
        int grid2 = (half + block - 1) / block;
        gather_kernel<<<grid2, block, 0, stream>>>(
            (const v4f*)table, fidx, (v4f*)out, M4, half);
    } else {
        int block = 256;
        int grid = (M + block - 1) / block;
        learnpose_fused_kernel<<<grid, block, 0, stream>>>(r, t, init_c2w, fidx, out, M);
    }
}